// Round 1
// baseline (496.693 us; speedup 1.0000x reference)
//
#include <hip/hip_runtime.h>

#define NEGV -10000000000.0f
constexpr int Bn = 64, Tn = 512, Ln = 64;

__launch_bounds__(64)
__global__ void crf_fwd_kernel(const float* __restrict__ em,
                               const float* __restrict__ tr,
                               const int* __restrict__ lens,
                               float* __restrict__ out) {
    const int b = blockIdx.x;
    const int j = threadIdx.x;          // 0..63, column owned by this lane

    __shared__ alignas(16) float uLDS[Ln];

    // ---- Preload E column j: E[i] = exp(trans[i][j]) (constant over all steps).
    // exp(NEG) underflows to exactly 0 -> masked transitions contribute nothing.
    float E[Ln];
#pragma unroll
    for (int i = 0; i < Ln; ++i) E[i] = __expf(tr[i * Ln + j]);

    const float trSj = tr[j];                 // transition[START][j]
    const float trEj = tr[j * Ln + (Ln - 1)]; // transition[j][END]
    const int len = lens[b];
    const bool edge = (j == 0) || (j == Ln - 1);

    const float* emb = em + (size_t)b * Tn * Ln;
    float* outb = out + (size_t)b * Tn * Ln;

    // ---- 4-deep emission prefetch ring (override START/END cols to NEG at load)
    float emq[4];
#pragma unroll
    for (int tt = 0; tt < 4; ++tt) {
        float v = emb[tt * Ln + j];
        emq[tt] = edge ? NEGV : v;
    }

    float a = 0.0f;      // alpha_t[j] (this lane's column)
    float M = 0.0f;      // exact max over alpha_{t-1}
    float aLast = 0.0f;  // alpha at t = len-1

#pragma unroll 4
    for (int t = 0; t < Tn; ++t) {
        const float em_t = emq[t & 3];
        const int tp = t + 4;
        if (tp < Tn) {                       // prefetch 4 steps ahead
            float v = emb[tp * Ln + j];
            emq[tp & 3] = edge ? NEGV : v;
        }

        if (t == 0) {
            // alpha0[j] = trans[START][j] + em'[0][j]  (same op order as reference)
            a = trSj + em_t;
        } else {
            // u_i = exp(alpha_{t-1}[i] - M); broadcast via LDS (wave-internal)
            float u = __expf(a - M);
            uLDS[j] = u;
            __asm__ volatile("s_waitcnt lgkmcnt(0)" ::: "memory");

            float acc0 = 0.0f, acc1 = 0.0f, acc2 = 0.0f, acc3 = 0.0f;
            const float4* u4 = reinterpret_cast<const float4*>(uLDS);
#pragma unroll
            for (int i4 = 0; i4 < 16; ++i4) {
                float4 uv = u4[i4];          // same addr all lanes -> LDS broadcast
                acc0 = fmaf(uv.x, E[4 * i4 + 0], acc0);
                acc1 = fmaf(uv.y, E[4 * i4 + 1], acc1);
                acc2 = fmaf(uv.z, E[4 * i4 + 2], acc2);
                acc3 = fmaf(uv.w, E[4 * i4 + 3], acc3);
            }
            float S = (acc0 + acc1) + (acc2 + acc3);
            float lg = __logf(S);
            lg = (S > 0.0f) ? lg : NEGV;     // dead column (j==START): S==0 exactly
            a = em_t + (M + lg);
        }

        outb[t * Ln + j] = a;                // store alpha (fire-and-forget)
        if (t == len - 1) aLast = a;

        // exact wave-max of alpha_t for next step's scaling
        float m = a;
#pragma unroll
        for (int off = 32; off > 0; off >>= 1)
            m = fmaxf(m, __shfl_xor(m, off, 64));
        M = m;
    }

    // ---- log_Z[b] = logsumexp_j(alpha[len-1][j] + trans[j][END])
    float last = aLast + trEj;
    float m2 = last;
#pragma unroll
    for (int off = 32; off > 0; off >>= 1)
        m2 = fmaxf(m2, __shfl_xor(m2, off, 64));
    float e2 = __expf(last - m2);
#pragma unroll
    for (int off = 32; off > 0; off >>= 1)
        e2 += __shfl_xor(e2, off, 64);
    if (j == 0) out[(size_t)Bn * Tn * Ln + b] = m2 + __logf(e2);
}

extern "C" void kernel_launch(void* const* d_in, const int* in_sizes, int n_in,
                              void* d_out, int out_size, void* d_ws, size_t ws_size,
                              hipStream_t stream) {
    const float* em = (const float*)d_in[0];
    const float* tr = (const float*)d_in[1];
    const int* lens = (const int*)d_in[2];
    float* out = (float*)d_out;
    crf_fwd_kernel<<<dim3(Bn), dim3(64), 0, stream>>>(em, tr, lens, out);
}

// Round 2
// 361.891 us; speedup vs baseline: 1.3725x; 1.3725x over previous
//
#include <hip/hip_runtime.h>

#define NEGV -10000000000.0f
constexpr int Bn = 64, Tn = 512, Ln = 64;

__launch_bounds__(64)
__global__ void crf_fwd_kernel(const float* __restrict__ em,
                               const float* __restrict__ tr,
                               const int* __restrict__ lens,
                               float* __restrict__ out) {
    const int b = blockIdx.x;
    const int j = threadIdx.x;          // 0..63, label column owned by this lane

    __shared__ alignas(16) float uLDS[Ln];

    // E[i] = exp(trans[i][j]) — constant over all steps; exp(NEG) -> exactly 0.
    float E[Ln];
#pragma unroll
    for (int i = 0; i < Ln; ++i) E[i] = __expf(tr[i * Ln + j]);

    const float trSj = tr[j];                 // transition[START][j]
    const float trEj = tr[j * Ln + (Ln - 1)]; // transition[j][END]
    const int len = lens[b];
    const bool edge = (j == 0) || (j == Ln - 1);

    const float* emb = em + (size_t)b * Tn * Ln;
    float* outb = out + (size_t)b * Tn * Ln;

    // 4-deep emission prefetch ring (START/END columns forced to NEG at load)
    float emq[4];
#pragma unroll
    for (int tt = 0; tt < 4; ++tt) {
        float v = emb[tt * Ln + j];
        emq[tt] = edge ? NEGV : v;
    }

    // ---- t = 0 (peeled): alpha0 = trans[START][:] + em'_0
    float a = trSj + emq[0];
    outb[j] = a;
    float aPrev = a;                    // alpha_{t-1}[j]
    float aLast = a;
    float mPrev = __shfl(a, 1, 64);     // m_0 = alpha_0[1]  (lane 1 never masked)
    float u = __expf(a - mPrev);        // u_0 = exp(alpha_0 - m_0)

    // Recurrence chain per step is ONLY: u = S*c -> ds_write -> ds_read x16 -> FMA -> S.
    // exp/log/shuffle all run off-chain (overlap the LDS read latency).
#pragma unroll 4
    for (int t = 1; t < Tn; ++t) {
        uLDS[j] = u;                    // u_{t-1}; DS ops are in-order per wave

        const float em_t = emq[t & 3];
        const int tp = t + 4;
        if (tp < Tn) {                  // prefetch 4 steps ahead (slot reused after read)
            float v = emb[tp * Ln + j];
            emq[tp & 3] = edge ? NEGV : v;
        }

        // off-chain: scale for u_t, and the fold-in factor c_t
        float mNext = __shfl(aPrev, 1, 64);            // m_t = alpha_{t-1}[1]
        float c = __expf(em_t + (mPrev - mNext));      // edge: em=NEG -> c = 0 -> u_t = 0

        float acc0 = 0.0f, acc1 = 0.0f, acc2 = 0.0f, acc3 = 0.0f;
        const float4* u4 = reinterpret_cast<const float4*>(uLDS);
#pragma unroll
        for (int i4 = 0; i4 < 16; ++i4) {
            float4 uv = u4[i4];         // same addr across lanes -> LDS broadcast
            acc0 = fmaf(uv.x, E[4 * i4 + 0], acc0);
            acc1 = fmaf(uv.y, E[4 * i4 + 1], acc1);
            acc2 = fmaf(uv.z, E[4 * i4 + 2], acc2);
            acc3 = fmaf(uv.w, E[4 * i4 + 3], acc3);
        }
        float S = (acc0 + acc1) + (acc2 + acc3);

        // output alpha_t — off the recurrence chain (log not needed for u_t)
        float lg = __logf(S);
        lg = (S > 0.0f) ? lg : NEGV;    // dead column (j==START): S == 0 exactly
        float a_t = em_t + (mPrev + lg);
        outb[t * Ln + j] = a_t;
        if (t == len - 1) aLast = a_t;

        // THE chain: one multiply
        u = S * c;                      // u_t = exp(alpha_t - m_t), algebraically
        aPrev = a_t;
        mPrev = mNext;
    }

    // ---- log_Z[b] = logsumexp_j(alpha[len-1][j] + trans[j][END])
    float last = aLast + trEj;
    float m2 = last;
#pragma unroll
    for (int off = 32; off > 0; off >>= 1)
        m2 = fmaxf(m2, __shfl_xor(m2, off, 64));
    float e2 = __expf(last - m2);
#pragma unroll
    for (int off = 32; off > 0; off >>= 1)
        e2 += __shfl_xor(e2, off, 64);
    if (j == 0) out[(size_t)Bn * Tn * Ln + b] = m2 + __logf(e2);
}

extern "C" void kernel_launch(void* const* d_in, const int* in_sizes, int n_in,
                              void* d_out, int out_size, void* d_ws, size_t ws_size,
                              hipStream_t stream) {
    const float* em = (const float*)d_in[0];
    const float* tr = (const float*)d_in[1];
    const int* lens = (const int*)d_in[2];
    float* out = (float*)d_out;
    crf_fwd_kernel<<<dim3(Bn), dim3(64), 0, stream>>>(em, tr, lens, out);
}

// Round 3
// 143.268 us; speedup vs baseline: 3.4669x; 2.5260x over previous
//
#include <hip/hip_runtime.h>

#define NEGV -10000000000.0f
constexpr int Bn = 64, Tn = 512, Ln = 64;
constexpr int CK = 32;          // chunk length
constexpr int NC = 16;          // number of chunks
constexpr int QP = 68;          // padded LDS row pitch (bf16 elems): 2-way-bank-free, 8B aligned

typedef float f32x16 __attribute__((ext_vector_type(16)));
typedef __bf16 bf16x8 __attribute__((ext_vector_type(8)));
typedef unsigned int u32;
typedef unsigned short u16;

__device__ inline float waveMaxF(float v) {
#pragma unroll
    for (int off = 32; off > 0; off >>= 1)
        v = fmaxf(v, __shfl_xor(v, off, 64));
    return v;
}
// pack two f32 -> bf16 pair (round-ish: +0x8000 truncate; values are finite & >= 0 here)
__device__ inline u32 packbf(float a, float b) {
    u32 ua = __float_as_uint(a) + 0x8000u;
    u32 ub = __float_as_uint(b) + 0x8000u;
    return (ua >> 16) | (ub & 0xffff0000u);
}
__device__ inline float lo16f(u32 d) { return __uint_as_float(d << 16); }
__device__ inline float hi16f(u32 d) { return __uint_as_float(d & 0xffff0000u); }

// ---------------- the serial matvec chunk step (round-2 verified structure) -------------
// state: aPrev (alpha[j]), mPrev (lagged scale), u (= exp(alpha - mPrev))
// Executes timesteps [t0, t0+CK) given entry state; writes alphas; tracks aLast at len-1.
template <bool FIRST>
__device__ void chunk_scan(const float* __restrict__ emb, const float* __restrict__ tr,
                           float* __restrict__ outb, float* uLDS,
                           const float* Ecol,            // E[i] = exp(tr[i][j]), 64 regs
                           float entry,                  // FIRST: unused; else alpha_{t0-1}[j]
                           int t0, int j, int len, float* aLastOut, float trSj) {
    const bool edge = (j == 0) || (j == Ln - 1);
    float emq[4];
#pragma unroll
    for (int tt = 0; tt < 4; ++tt) {
        float v = emb[(t0 + tt) * Ln + j];
        emq[tt] = edge ? NEGV : v;
    }
    float aPrev, mPrev, u;
    int tauStart;
    if (FIRST) {
        float a0 = trSj + emq[0];
        outb[t0 * Ln + j] = a0;
        aPrev = a0;
        mPrev = __shfl(a0, 1, 64);
        u = __expf(a0 - mPrev);
        tauStart = 1;
    } else {
        aPrev = entry;
        mPrev = __shfl(entry, 1, 64);
        u = __expf(entry - mPrev);
        tauStart = 0;
    }
    float aLast = *aLastOut;
#pragma unroll 4
    for (int tau = tauStart; tau < CK; ++tau) {
        const int t = t0 + tau;
        uLDS[j] = u;
        const float em_t = emq[tau & 3];
        const int tp = tau + 4;
        if (tp < CK) {
            float v = emb[(t0 + tp) * Ln + j];
            emq[tp & 3] = edge ? NEGV : v;
        }
        float mNext = __shfl(aPrev, 1, 64);
        float cf = __expf(em_t + (mPrev - mNext));
        float acc0 = 0.f, acc1 = 0.f, acc2 = 0.f, acc3 = 0.f;
        const float4* u4 = reinterpret_cast<const float4*>(uLDS);
#pragma unroll
        for (int i4 = 0; i4 < 16; ++i4) {
            float4 uv = u4[i4];
            acc0 = fmaf(uv.x, Ecol[4 * i4 + 0], acc0);
            acc1 = fmaf(uv.y, Ecol[4 * i4 + 1], acc1);
            acc2 = fmaf(uv.z, Ecol[4 * i4 + 2], acc2);
            acc3 = fmaf(uv.w, Ecol[4 * i4 + 3], acc3);
        }
        float S = (acc0 + acc1) + (acc2 + acc3);
        float lg = __logf(S);
        lg = (S > 0.f) ? lg : NEGV;
        float a_t = em_t + (mPrev + lg);
        outb[t * Ln + j] = a_t;
        if (t == len - 1) aLast = a_t;
        u = S * cf;
        aPrev = a_t;
        mPrev = mNext;
    }
    *aLastOut = aLast;
    // return final alpha through entry slot trick: caller reads aPrev via aLastOut? no —
    // caller needs alpha_{t0+CK-1}: stash in uLDS then read (wave-uniform path avoided):
    uLDS[j] = aPrev;   // caller reads uLDS[j] right after (wave in-order)
}

// ================= PASS A: chunk-0 direct scan + transfer matrices (MFMA) ================
__global__ __launch_bounds__(64) void crf_passA(const float* __restrict__ em,
                                                const float* __restrict__ tr,
                                                float* __restrict__ out,
                                                float* __restrict__ wsE,
                                                float* __restrict__ wsS) {
    const int b = blockIdx.x & 63;
    const int cix = blockIdx.x >> 6;         // 0..15
    const int L = threadIdx.x;               // lane
    __shared__ alignas(16) float gtab[CK * 64];       // 8 KiB
    __shared__ alignas(16) u16 Qlds[64 * QP];         // 8.5 KiB, layout [n][k]
    __shared__ alignas(16) float uLDS[64];

    if (cix == 0) {
        // ---- chunk 0: direct scan t=0..31 (entry known exactly)
        float Ecol[Ln];
#pragma unroll
        for (int i = 0; i < Ln; ++i) Ecol[i] = __expf(tr[i * Ln + L]);
        const float trSj = tr[L];
        const float* emb = em + (size_t)b * Tn * Ln;
        float* outb = out + (size_t)b * Tn * Ln;
        float dummyLast = 0.f;
        chunk_scan<true>(emb, tr, outb, uLDS, Ecol, 0.f, 0, L, /*len*/ -12345, &dummyLast, trSj);
        // final alpha_31 is in uLDS[L]
        wsE[b * 1024 + 1 * 64 + L] = uLDS[L];
        return;
    }

    // ---- transfer-matrix task for chunk cix (t in [32*cix, 32*cix+32))
    const int t0 = CK * cix;
    const int h = L >> 5;                    // lane half
    const int c31 = L & 31;

    // phase 0: g table  g[tau][k] = exp(em'[t0+tau][k] - s_tau),  sSum = sum s_tau
    float sSum = 0.f;
#pragma unroll 4
    for (int tau = 0; tau < CK; ++tau) {
        float v = em[((size_t)b * Tn + (t0 + tau)) * Ln + L];
        if (L == 0 || L == Ln - 1) v = NEGV;
        float s = waveMaxF(v);
        gtab[tau * 64 + L] = __expf(v - s);
        sSum += s;
    }

    // A-frags: E^T in bf16, A[m][k] = exp(tr[k][m]), m = 32I + c31, k = 16kc + 8h + idx
    uint4 Ap[2][4];
#pragma unroll
    for (int I = 0; I < 2; ++I)
#pragma unroll
        for (int kc = 0; kc < 4; ++kc) {
            float e[8];
#pragma unroll
            for (int q = 0; q < 8; ++q) {
                int k = 16 * kc + 8 * h + q;
                e[q] = __expf(tr[k * Ln + 32 * I + c31]);
            }
            Ap[I][kc] = make_uint4(packbf(e[0], e[1]), packbf(e[2], e[3]),
                                   packbf(e[4], e[5]), packbf(e[6], e[7]));
        }

    // Q0[k][n] = exp(tr[n][k]) * g0[k]; lane owns row n = L of Qlds[n][k]
    float mxPrev;
    {
        float mx0 = 0.f;
#pragma unroll
        for (int k4 = 0; k4 < 16; ++k4) {
            float v0 = __expf(tr[L * Ln + 4 * k4 + 0]) * gtab[4 * k4 + 0];
            float v1 = __expf(tr[L * Ln + 4 * k4 + 1]) * gtab[4 * k4 + 1];
            float v2 = __expf(tr[L * Ln + 4 * k4 + 2]) * gtab[4 * k4 + 2];
            float v3 = __expf(tr[L * Ln + 4 * k4 + 3]) * gtab[4 * k4 + 3];
            mx0 = fmaxf(mx0, fmaxf(fmaxf(v0, v1), fmaxf(v2, v3)));
            uint2 w;
            w.x = packbf(v0, v1);
            w.y = packbf(v2, v3);
            *(uint2*)&Qlds[L * QP + 4 * k4] = w;
        }
        mxPrev = waveMaxF(mx0);
    }
    float sigma = sSum;
    const f32x16 Z = (f32x16)(0.0f);

    for (int tau = 1; tau < CK; ++tau) {
        // B-frags from Qlds: B[k][n], n = 32J + c31, k = 16kc + 8h + idx
        uint4 Bp[2][4];
#pragma unroll
        for (int J = 0; J < 2; ++J)
#pragma unroll
            for (int kc = 0; kc < 4; ++kc) {
                const u16* p = &Qlds[(32 * J + c31) * QP + 16 * kc + 8 * h];
                uint2 q0 = *(const uint2*)(p);
                uint2 q1 = *(const uint2*)(p + 4);
                Bp[J][kc] = make_uint4(q0.x, q0.y, q1.x, q1.y);
            }
        // R = E^T * Qhat  (4 output tiles)
        f32x16 acc[2][2];
#pragma unroll
        for (int I = 0; I < 2; ++I)
#pragma unroll
            for (int J = 0; J < 2; ++J) {
                f32x16 a = Z;
#pragma unroll
                for (int kc = 0; kc < 4; ++kc)
                    a = __builtin_amdgcn_mfma_f32_32x32x16_bf16(
                        __builtin_bit_cast(bf16x8, Ap[I][kc]),
                        __builtin_bit_cast(bf16x8, Bp[J][kc]), a, 0, 0, 0);
                acc[I][J] = a;
            }
        // Qhat_tau[k][n] = rho * g_tau[k] * R[k][n]; lagged rescale
        float rho = 1.0f / mxPrev;
        sigma += __logf(mxPrev);
        float nmx = 0.f;
#pragma unroll
        for (int I = 0; I < 2; ++I)
#pragma unroll
            for (int rg = 0; rg < 4; ++rg) {
                int k0 = 32 * I + 8 * rg + 4 * h;
                float4 G = *(const float4*)&gtab[tau * 64 + k0];
                float g0 = G.x * rho, g1 = G.y * rho, g2 = G.z * rho, g3 = G.w * rho;
#pragma unroll
                for (int J = 0; J < 2; ++J) {
                    float v0 = acc[I][J][4 * rg + 0] * g0;
                    float v1 = acc[I][J][4 * rg + 1] * g1;
                    float v2 = acc[I][J][4 * rg + 2] * g2;
                    float v3 = acc[I][J][4 * rg + 3] * g3;
                    nmx = fmaxf(nmx, fmaxf(fmaxf(v0, v1), fmaxf(v2, v3)));
                    uint2 w;
                    w.x = packbf(v0, v1);
                    w.y = packbf(v2, v3);
                    *(uint2*)&Qlds[(32 * J + c31) * QP + k0] = w;
                }
            }
        mxPrev = waveMaxF(nmx);
    }

    // finalize: per-row (= T column j = L) normalization, store bf16 row + sigma_j
    {
        float rv[64];
        float rmax = 0.f;
#pragma unroll
        for (int n = 0; n < 64; ++n) {
            float v = __uint_as_float(((u32)Qlds[n * QP + L]) << 16);
            rv[n] = v;
            rmax = fmaxf(rmax, v);
        }
        float inv = (rmax > 0.f) ? 1.0f / rmax : 0.f;
        float sj = (rmax > 0.f) ? sigma + __logf(rmax) : 0.f;
        u32* og = (u32*)out + (size_t)b * (Tn * Ln) + (size_t)cix * (CK * Ln) + L * 32;
#pragma unroll
        for (int w8 = 0; w8 < 8; ++w8) {
            uint4 w;
            w.x = packbf(rv[8 * w8 + 0] * inv, rv[8 * w8 + 1] * inv);
            w.y = packbf(rv[8 * w8 + 2] * inv, rv[8 * w8 + 3] * inv);
            w.z = packbf(rv[8 * w8 + 4] * inv, rv[8 * w8 + 5] * inv);
            w.w = packbf(rv[8 * w8 + 6] * inv, rv[8 * w8 + 7] * inv);
            *(uint4*)(og + 4 * w8) = w;
        }
        wsS[b * 1024 + cix * 64 + L] = sj;
    }
}

// ================= PASS B: serial boundary combine across chunks =================
__global__ __launch_bounds__(64) void crf_passB(const float* __restrict__ out,
                                                float* __restrict__ wsE,
                                                const float* __restrict__ wsS) {
    const int b = blockIdx.x;
    const int j = threadIdx.x;
    __shared__ alignas(16) float uL[64];
    const u32* Qbase = (const u32*)out + (size_t)b * (Tn * Ln);

    float e = wsE[b * 1024 + 1 * 64 + j];
    uint4 nxt[8];
    float signxt = wsS[b * 1024 + 1 * 64 + j];
#pragma unroll
    for (int r = 0; r < 8; ++r) nxt[r] = *(const uint4*)(Qbase + 1 * (CK * Ln) + j * 32 + 4 * r);

#pragma unroll
    for (int c = 1; c <= 14; ++c) {
        uint4 cur[8];
#pragma unroll
        for (int r = 0; r < 8; ++r) cur[r] = nxt[r];
        float sig = signxt;
        if (c < 14) {
#pragma unroll
            for (int r = 0; r < 8; ++r)
                nxt[r] = *(const uint4*)(Qbase + (size_t)(c + 1) * (CK * Ln) + j * 32 + 4 * r);
            signxt = wsS[b * 1024 + (c + 1) * 64 + j];
        }
        float m = __shfl(e, 1, 64);
        uL[j] = __expf(e - m);
        const float4* u4 = reinterpret_cast<const float4*>(uL);
        float S = 0.f;
#pragma unroll
        for (int i4 = 0; i4 < 16; ++i4) {
            float4 uv = u4[i4];
            u32 d0 = ((const u32*)cur)[2 * i4];
            u32 d1 = ((const u32*)cur)[2 * i4 + 1];
            S = fmaf(uv.x, lo16f(d0), S);
            S = fmaf(uv.y, hi16f(d0), S);
            S = fmaf(uv.z, lo16f(d1), S);
            S = fmaf(uv.w, hi16f(d1), S);
        }
        float a;
        if (S > 0.f) a = m + sig + __logf(S);
        else a = m + NEGV + ((j == 0) ? NEGV : 0.f);
        e = a;
        wsE[b * 1024 + (c + 1) * 64 + j] = e;
    }
}

// ================= PASS C: per-chunk alpha recompute + logZ =================
__global__ __launch_bounds__(64) void crf_passC(const float* __restrict__ em,
                                                const float* __restrict__ tr,
                                                const int* __restrict__ lens,
                                                float* __restrict__ out,
                                                const float* __restrict__ wsE) {
    const int b = blockIdx.x & 63;
    const int cix = 1 + (blockIdx.x >> 6);   // 1..15
    const int j = threadIdx.x;
    __shared__ alignas(16) float uLDS[64];

    float Ecol[Ln];
#pragma unroll
    for (int i = 0; i < Ln; ++i) Ecol[i] = __expf(tr[i * Ln + j]);
    const float trEj = tr[j * Ln + (Ln - 1)];
    const int len = lens[b];
    const float* emb = em + (size_t)b * Tn * Ln;
    float* outb = out + (size_t)b * Tn * Ln;
    const float entry = wsE[b * 1024 + cix * 64 + j];

    float aLast = 0.f;
    chunk_scan<false>(emb, tr, outb, uLDS, Ecol, entry, CK * cix, j, len, &aLast, 0.f);

    if (((len - 1) >> 5) == cix) {
        float last = aLast + trEj;
        float m2 = last;
#pragma unroll
        for (int off = 32; off > 0; off >>= 1)
            m2 = fmaxf(m2, __shfl_xor(m2, off, 64));
        float e2 = __expf(last - m2);
#pragma unroll
        for (int off = 32; off > 0; off >>= 1)
            e2 += __shfl_xor(e2, off, 64);
        if (j == 0) out[(size_t)Bn * Tn * Ln + b] = m2 + __logf(e2);
    }
}

// ================= fallback: round-2 single kernel =================
__global__ __launch_bounds__(64) void crf_fallback(const float* __restrict__ em,
                                                   const float* __restrict__ tr,
                                                   const int* __restrict__ lens,
                                                   float* __restrict__ out) {
    const int b = blockIdx.x;
    const int j = threadIdx.x;
    __shared__ alignas(16) float uLDS[Ln];
    float E[Ln];
#pragma unroll
    for (int i = 0; i < Ln; ++i) E[i] = __expf(tr[i * Ln + j]);
    const float trSj = tr[j];
    const float trEj = tr[j * Ln + (Ln - 1)];
    const int len = lens[b];
    const bool edge = (j == 0) || (j == Ln - 1);
    const float* emb = em + (size_t)b * Tn * Ln;
    float* outb = out + (size_t)b * Tn * Ln;
    float emq[4];
#pragma unroll
    for (int tt = 0; tt < 4; ++tt) {
        float v = emb[tt * Ln + j];
        emq[tt] = edge ? NEGV : v;
    }
    float a = trSj + emq[0];
    outb[j] = a;
    float aPrev = a, aLast = a;
    float mPrev = __shfl(a, 1, 64);
    float u = __expf(a - mPrev);
#pragma unroll 4
    for (int t = 1; t < Tn; ++t) {
        uLDS[j] = u;
        const float em_t = emq[t & 3];
        const int tp = t + 4;
        if (tp < Tn) {
            float v = emb[tp * Ln + j];
            emq[tp & 3] = edge ? NEGV : v;
        }
        float mNext = __shfl(aPrev, 1, 64);
        float cf = __expf(em_t + (mPrev - mNext));
        float acc0 = 0.f, acc1 = 0.f, acc2 = 0.f, acc3 = 0.f;
        const float4* u4 = reinterpret_cast<const float4*>(uLDS);
#pragma unroll
        for (int i4 = 0; i4 < 16; ++i4) {
            float4 uv = u4[i4];
            acc0 = fmaf(uv.x, E[4 * i4 + 0], acc0);
            acc1 = fmaf(uv.y, E[4 * i4 + 1], acc1);
            acc2 = fmaf(uv.z, E[4 * i4 + 2], acc2);
            acc3 = fmaf(uv.w, E[4 * i4 + 3], acc3);
        }
        float S = (acc0 + acc1) + (acc2 + acc3);
        float lg = __logf(S);
        lg = (S > 0.f) ? lg : NEGV;
        float a_t = em_t + (mPrev + lg);
        outb[t * Ln + j] = a_t;
        if (t == len - 1) aLast = a_t;
        u = S * cf;
        aPrev = a_t;
        mPrev = mNext;
    }
    float last = aLast + trEj;
    float m2 = last;
#pragma unroll
    for (int off = 32; off > 0; off >>= 1)
        m2 = fmaxf(m2, __shfl_xor(m2, off, 64));
    float e2 = __expf(last - m2);
#pragma unroll
    for (int off = 32; off > 0; off >>= 1)
        e2 += __shfl_xor(e2, off, 64);
    if (j == 0) out[(size_t)Bn * Tn * Ln + b] = m2 + __logf(e2);
}

extern "C" void kernel_launch(void* const* d_in, const int* in_sizes, int n_in,
                              void* d_out, int out_size, void* d_ws, size_t ws_size,
                              hipStream_t stream) {
    const float* em = (const float*)d_in[0];
    const float* tr = (const float*)d_in[1];
    const int* lens = (const int*)d_in[2];
    float* out = (float*)d_out;
    const size_t wsNeed = 2u * 64 * 16 * 64 * sizeof(float);   // 512 KiB
    if (ws_size >= wsNeed) {
        float* wsE = (float*)d_ws;
        float* wsS = wsE + 64 * 16 * 64;
        crf_passA<<<dim3(1024), dim3(64), 0, stream>>>(em, tr, out, wsE, wsS);
        crf_passB<<<dim3(64), dim3(64), 0, stream>>>(out, wsE, wsS);
        crf_passC<<<dim3(960), dim3(64), 0, stream>>>(em, tr, lens, out, wsE);
    } else {
        crf_fallback<<<dim3(Bn), dim3(64), 0, stream>>>(em, tr, lens, out);
    }
}

// Round 4
// 134.771 us; speedup vs baseline: 3.6854x; 1.0630x over previous
//
#include <hip/hip_runtime.h>

#define NEGV -10000000000.0f
constexpr int Bn = 64, Tn = 512, Ln = 64;
constexpr int CK = 32;          // chunk length
constexpr int NC = 16;          // number of chunks
constexpr int QP = 68;          // padded LDS row pitch (bf16 elems)

typedef float f32x16 __attribute__((ext_vector_type(16)));
typedef __bf16 bf16x8 __attribute__((ext_vector_type(8)));
typedef unsigned int u32;
typedef unsigned short u16;

__device__ inline float waveMaxF(float v) {
#pragma unroll
    for (int off = 32; off > 0; off >>= 1)
        v = fmaxf(v, __shfl_xor(v, off, 64));
    return v;
}
__device__ inline u32 packbf(float a, float b) {
    u32 ua = __float_as_uint(a) + 0x8000u;
    u32 ub = __float_as_uint(b) + 0x8000u;
    return (ua >> 16) | (ub & 0xffff0000u);
}
__device__ inline float lo16f(u32 d) { return __uint_as_float(d << 16); }
__device__ inline float hi16f(u32 d) { return __uint_as_float(d & 0xffff0000u); }

// ---------------- serial matvec chunk scan (round-2/3 verified structure) -------------
template <bool FIRST>
__device__ void chunk_scan(const float* __restrict__ emb,
                           float* __restrict__ outb, float* uLDS,
                           const float* Ecol, float entry, int t0, int j, int len,
                           float trSj, float* aLastOut, float* aFinalOut) {
    const bool edge = (j == 0) || (j == Ln - 1);
    float emq[4];
#pragma unroll
    for (int tt = 0; tt < 4; ++tt) {
        float v = emb[(t0 + tt) * Ln + j];
        emq[tt] = edge ? NEGV : v;
    }
    float aPrev, mPrev, u;
    int tauStart;
    if (FIRST) {
        float a0 = trSj + emq[0];
        outb[t0 * Ln + j] = a0;
        aPrev = a0;
        mPrev = __shfl(a0, 1, 64);
        u = __expf(a0 - mPrev);
        tauStart = 1;
    } else {
        aPrev = entry;
        mPrev = __shfl(entry, 1, 64);
        u = __expf(entry - mPrev);
        tauStart = 0;
    }
    float aLast = *aLastOut;
#pragma unroll 4
    for (int tau = tauStart; tau < CK; ++tau) {
        const int t = t0 + tau;
        uLDS[j] = u;
        const float em_t = emq[tau & 3];
        const int tp = tau + 4;
        if (tp < CK) {
            float v = emb[(t0 + tp) * Ln + j];
            emq[tp & 3] = edge ? NEGV : v;
        }
        float mNext = __shfl(aPrev, 1, 64);
        float cf = __expf(em_t + (mPrev - mNext));
        float acc0 = 0.f, acc1 = 0.f, acc2 = 0.f, acc3 = 0.f;
        const float4* u4 = reinterpret_cast<const float4*>(uLDS);
#pragma unroll
        for (int i4 = 0; i4 < 16; ++i4) {
            float4 uv = u4[i4];
            acc0 = fmaf(uv.x, Ecol[4 * i4 + 0], acc0);
            acc1 = fmaf(uv.y, Ecol[4 * i4 + 1], acc1);
            acc2 = fmaf(uv.z, Ecol[4 * i4 + 2], acc2);
            acc3 = fmaf(uv.w, Ecol[4 * i4 + 3], acc3);
        }
        float S = (acc0 + acc1) + (acc2 + acc3);
        float lg = __logf(S);
        lg = (S > 0.f) ? lg : NEGV;
        float a_t = em_t + (mPrev + lg);
        outb[t * Ln + j] = a_t;
        if (t == len - 1) aLast = a_t;
        u = S * cf;
        aPrev = a_t;
        mPrev = mNext;
    }
    *aLastOut = aLast;
    *aFinalOut = aPrev;
}

// ================= PASS A: chunk-0 scan + transfer matrices (2 waves, col-split) =========
__global__ __launch_bounds__(128) void crf_passA(const float* __restrict__ em,
                                                 const float* __restrict__ tr,
                                                 float* __restrict__ out,
                                                 float* __restrict__ wsE,
                                                 float* __restrict__ wsS) {
    const int b = blockIdx.x & 63;
    const int cix = blockIdx.x >> 6;         // 0..15
    const int J = threadIdx.x >> 6;          // wave id = column group
    const int L = threadIdx.x & 63;          // lane
    __shared__ alignas(16) float gtab[CK * 64];       // 8 KiB
    __shared__ alignas(16) u16 Qlds[64 * QP];         // 8.5 KiB, [n][k]
    __shared__ alignas(16) float uLDS[64];
    __shared__ float sLDS[2];
    __shared__ float sigLDS[2];

    if (cix == 0) {
        if (J == 1) return;                  // no barriers on this path
        float Ecol[Ln];
#pragma unroll
        for (int i = 0; i < Ln; ++i) Ecol[i] = __expf(tr[i * Ln + L]);
        const float trSj = tr[L];
        const float* emb = em + (size_t)b * Tn * Ln;
        float* outb = out + (size_t)b * Tn * Ln;
        float dummyLast = 0.f, aFinal;
        chunk_scan<true>(emb, outb, uLDS, Ecol, 0.f, 0, L, /*len*/ -1, trSj, &dummyLast, &aFinal);
        wsE[b * 1024 + 1 * 64 + L] = aFinal;
        return;
    }

    const int t0 = CK * cix;
    const int c31 = L & 31;
    const int h = L >> 5;

    // ---- gtab fill (split by wave) with VECTORIZED butterfly row-max
    {
        float orig[16], sv[16];
        const int tb = t0 + 16 * J;
#pragma unroll
        for (int r = 0; r < 16; ++r) {
            float v = em[((size_t)b * Tn + (tb + r)) * Ln + L];
            if (L == 0 || L == Ln - 1) v = NEGV;
            orig[r] = v;
            sv[r] = v;
        }
#pragma unroll
        for (int off = 32; off > 0; off >>= 1) {
#pragma unroll
            for (int r = 0; r < 16; ++r)
                sv[r] = fmaxf(sv[r], __shfl_xor(sv[r], off, 64));
        }
        float ssum = 0.f;
#pragma unroll
        for (int r = 0; r < 16; ++r) {
            gtab[(16 * J + r) * 64 + L] = __expf(orig[r] - sv[r]);
            ssum += sv[r];
        }
        if (L == 0) sLDS[J] = ssum;
    }
    __syncthreads();
    const float sSum = sLDS[0] + sLDS[1];

    // ---- A-frags: A[m][k] = exp(tr[k][m]), m = 32I + c31, k = 16kc + 8h + q
    uint4 Ap[2][4];
#pragma unroll
    for (int I = 0; I < 2; ++I)
#pragma unroll
        for (int kc = 0; kc < 4; ++kc) {
            float e[8];
#pragma unroll
            for (int q = 0; q < 8; ++q) {
                int k = 16 * kc + 8 * h + q;
                e[q] = __expf(tr[k * Ln + 32 * I + c31]);
            }
            Ap[I][kc] = make_uint4(packbf(e[0], e[1]), packbf(e[2], e[3]),
                                   packbf(e[4], e[5]), packbf(e[6], e[7]));
        }

    // ---- Q0: this wave's column n = 32J + c31, k-half h
    const int n = 32 * J + c31;
    {
        const float* trn = tr + n * Ln + 32 * h;
        const float* g0 = gtab + 32 * h;
#pragma unroll
        for (int k4 = 0; k4 < 8; ++k4) {
            float v0 = __expf(trn[4 * k4 + 0]) * g0[4 * k4 + 0];
            float v1 = __expf(trn[4 * k4 + 1]) * g0[4 * k4 + 1];
            float v2 = __expf(trn[4 * k4 + 2]) * g0[4 * k4 + 2];
            float v3 = __expf(trn[4 * k4 + 3]) * g0[4 * k4 + 3];
            uint2 w;
            w.x = packbf(v0, v1);
            w.y = packbf(v2, v3);
            *(uint2*)&Qlds[n * QP + 32 * h + 4 * k4] = w;
        }
    }

    // ---- main loop: barrier-free (wave reads only rows it wrote); lag-2 periodic rescale
    float sig_w = 0.f;
    float wm = 1.0f;                         // first used at tau=4 (measured at tau=2)
    const f32x16 Z = (f32x16)(0.0f);
    for (int tau = 1; tau < CK; ++tau) {
        uint4 Bp[4];
#pragma unroll
        for (int kc = 0; kc < 4; ++kc) {
            const u16* p = &Qlds[n * QP + 16 * kc + 8 * h];
            uint2 q0 = *(const uint2*)(p);
            uint2 q1 = *(const uint2*)(p + 4);
            Bp[kc] = make_uint4(q0.x, q0.y, q1.x, q1.y);
        }
        f32x16 acc0 = Z, acc1 = Z;
#pragma unroll
        for (int kc = 0; kc < 4; ++kc) {
            acc0 = __builtin_amdgcn_mfma_f32_32x32x16_bf16(
                __builtin_bit_cast(bf16x8, Ap[0][kc]),
                __builtin_bit_cast(bf16x8, Bp[kc]), acc0, 0, 0, 0);
            acc1 = __builtin_amdgcn_mfma_f32_32x32x16_bf16(
                __builtin_bit_cast(bf16x8, Ap[1][kc]),
                __builtin_bit_cast(bf16x8, Bp[kc]), acc1, 0, 0, 0);
        }
        const bool doRescale = ((tau & 3) == 0);
        const bool doMeasure = ((tau & 3) == 2);
        float rr = 1.0f;
        if (doRescale) {
            rr = 1.0f / wm;
            sig_w += __logf(wm);
        }
        float lmax = 0.f;
#pragma unroll
        for (int I = 0; I < 2; ++I) {
#pragma unroll
            for (int rg = 0; rg < 4; ++rg) {
                const int k0 = 32 * I + 8 * rg + 4 * h;
                float4 G = *(const float4*)&gtab[tau * 64 + k0];
                float v0 = (I ? acc1 : acc0)[4 * rg + 0] * (G.x * rr);
                float v1 = (I ? acc1 : acc0)[4 * rg + 1] * (G.y * rr);
                float v2 = (I ? acc1 : acc0)[4 * rg + 2] * (G.z * rr);
                float v3 = (I ? acc1 : acc0)[4 * rg + 3] * (G.w * rr);
                if (doMeasure) lmax = fmaxf(lmax, fmaxf(fmaxf(v0, v1), fmaxf(v2, v3)));
                uint2 w;
                w.x = packbf(v0, v1);
                w.y = packbf(v2, v3);
                *(uint2*)&Qlds[n * QP + k0] = w;
            }
        }
        if (doMeasure) wm = waveMaxF(lmax);  // off-chain: used 2 steps later
    }

    // ---- reconcile per-wave scales, per-row normalize, store bf16 T-hat + sigma
    if (L == 0) sigLDS[J] = sSum + sig_w;
    __syncthreads();
    const float sg0 = sigLDS[0], sg1 = sigLDS[1];
    const float smax = fmaxf(sg0, sg1);
    const float fh = __expf((h ? sg1 : sg0) - smax);   // scale for this lane's n-half
    const int r = 32 * J + c31;                         // output row handled by this lane
    float rv[32];
    float lmaxr = 0.f;
#pragma unroll
    for (int i = 0; i < 32; ++i) {
        float v = __uint_as_float(((u32)Qlds[(32 * h + i) * QP + r]) << 16) * fh;
        rv[i] = v;
        lmaxr = fmaxf(lmaxr, v);
    }
    float rmax = fmaxf(lmaxr, __shfl_xor(lmaxr, 32, 64));
    float inv = (rmax > 0.f) ? 1.0f / rmax : 0.f;
    float sj = (rmax > 0.f) ? smax + __logf(rmax) : 0.f;
    u32* og = (u32*)out + (size_t)b * (Tn * Ln) + (size_t)cix * (CK * Ln) + r * 32 + h * 16;
#pragma unroll
    for (int w8 = 0; w8 < 4; ++w8) {
        uint4 w;
        w.x = packbf(rv[8 * w8 + 0] * inv, rv[8 * w8 + 1] * inv);
        w.y = packbf(rv[8 * w8 + 2] * inv, rv[8 * w8 + 3] * inv);
        w.z = packbf(rv[8 * w8 + 4] * inv, rv[8 * w8 + 5] * inv);
        w.w = packbf(rv[8 * w8 + 6] * inv, rv[8 * w8 + 7] * inv);
        *(uint4*)(og + 4 * w8) = w;
    }
    if (h == 0) wsS[b * 1024 + cix * 64 + r] = sj;
}

// ================= PASS B: serial boundary combine =================
__global__ __launch_bounds__(64) void crf_passB(const float* __restrict__ out,
                                                float* __restrict__ wsE,
                                                const float* __restrict__ wsS) {
    const int b = blockIdx.x;
    const int j = threadIdx.x;
    __shared__ alignas(16) float uL[64];
    const u32* Qbase = (const u32*)out + (size_t)b * (Tn * Ln);

    float e = wsE[b * 1024 + 1 * 64 + j];
    uint4 nxt[8];
    float signxt = wsS[b * 1024 + 1 * 64 + j];
#pragma unroll
    for (int r = 0; r < 8; ++r) nxt[r] = *(const uint4*)(Qbase + 1 * (CK * Ln) + j * 32 + 4 * r);

#pragma unroll
    for (int c = 1; c <= 14; ++c) {
        uint4 cur[8];
#pragma unroll
        for (int r = 0; r < 8; ++r) cur[r] = nxt[r];
        float sig = signxt;
        if (c < 14) {
#pragma unroll
            for (int r = 0; r < 8; ++r)
                nxt[r] = *(const uint4*)(Qbase + (size_t)(c + 1) * (CK * Ln) + j * 32 + 4 * r);
            signxt = wsS[b * 1024 + (c + 1) * 64 + j];
        }
        float m = __shfl(e, 1, 64);
        uL[j] = __expf(e - m);
        const float4* u4 = reinterpret_cast<const float4*>(uL);
        float S = 0.f;
#pragma unroll
        for (int i4 = 0; i4 < 16; ++i4) {
            float4 uv = u4[i4];
            u32 d0 = ((const u32*)cur)[2 * i4];
            u32 d1 = ((const u32*)cur)[2 * i4 + 1];
            S = fmaf(uv.x, lo16f(d0), S);
            S = fmaf(uv.y, hi16f(d0), S);
            S = fmaf(uv.z, lo16f(d1), S);
            S = fmaf(uv.w, hi16f(d1), S);
        }
        float a;
        if (S > 0.f) a = m + sig + __logf(S);
        else a = m + NEGV + ((j == 0) ? NEGV : 0.f);
        e = a;
        wsE[b * 1024 + (c + 1) * 64 + j] = e;
    }
}

// ================= PASS C: per-chunk alpha recompute + logZ =================
__global__ __launch_bounds__(64) void crf_passC(const float* __restrict__ em,
                                                const float* __restrict__ tr,
                                                const int* __restrict__ lens,
                                                float* __restrict__ out,
                                                const float* __restrict__ wsE) {
    const int b = blockIdx.x & 63;
    const int cix = 1 + (blockIdx.x >> 6);   // 1..15
    const int j = threadIdx.x;
    __shared__ alignas(16) float uLDS[64];

    float Ecol[Ln];
#pragma unroll
    for (int i = 0; i < Ln; ++i) Ecol[i] = __expf(tr[i * Ln + j]);
    const float trEj = tr[j * Ln + (Ln - 1)];
    const int len = lens[b];
    const float* emb = em + (size_t)b * Tn * Ln;
    float* outb = out + (size_t)b * Tn * Ln;
    const float entry = wsE[b * 1024 + cix * 64 + j];

    float aLast = 0.f, aFinal;
    chunk_scan<false>(emb, outb, uLDS, Ecol, entry, CK * cix, j, len, 0.f, &aLast, &aFinal);

    if (((len - 1) >> 5) == cix) {
        float last = aLast + trEj;
        float m2 = last;
#pragma unroll
        for (int off = 32; off > 0; off >>= 1)
            m2 = fmaxf(m2, __shfl_xor(m2, off, 64));
        float e2 = __expf(last - m2);
#pragma unroll
        for (int off = 32; off > 0; off >>= 1)
            e2 += __shfl_xor(e2, off, 64);
        if (j == 0) out[(size_t)Bn * Tn * Ln + b] = m2 + __logf(e2);
    }
}

// ================= fallback: round-2 single kernel =================
__global__ __launch_bounds__(64) void crf_fallback(const float* __restrict__ em,
                                                   const float* __restrict__ tr,
                                                   const int* __restrict__ lens,
                                                   float* __restrict__ out) {
    const int b = blockIdx.x;
    const int j = threadIdx.x;
    __shared__ alignas(16) float uLDS[Ln];
    float E[Ln];
#pragma unroll
    for (int i = 0; i < Ln; ++i) E[i] = __expf(tr[i * Ln + j]);
    const float trSj = tr[j];
    const float trEj = tr[j * Ln + (Ln - 1)];
    const int len = lens[b];
    const bool edge = (j == 0) || (j == Ln - 1);
    const float* emb = em + (size_t)b * Tn * Ln;
    float* outb = out + (size_t)b * Tn * Ln;
    float emq[4];
#pragma unroll
    for (int tt = 0; tt < 4; ++tt) {
        float v = emb[tt * Ln + j];
        emq[tt] = edge ? NEGV : v;
    }
    float a = trSj + emq[0];
    outb[j] = a;
    float aPrev = a, aLast = a;
    float mPrev = __shfl(a, 1, 64);
    float u = __expf(a - mPrev);
#pragma unroll 4
    for (int t = 1; t < Tn; ++t) {
        uLDS[j] = u;
        const float em_t = emq[t & 3];
        const int tp = t + 4;
        if (tp < Tn) {
            float v = emb[tp * Ln + j];
            emq[tp & 3] = edge ? NEGV : v;
        }
        float mNext = __shfl(aPrev, 1, 64);
        float cf = __expf(em_t + (mPrev - mNext));
        float acc0 = 0.f, acc1 = 0.f, acc2 = 0.f, acc3 = 0.f;
        const float4* u4 = reinterpret_cast<const float4*>(uLDS);
#pragma unroll
        for (int i4 = 0; i4 < 16; ++i4) {
            float4 uv = u4[i4];
            acc0 = fmaf(uv.x, E[4 * i4 + 0], acc0);
            acc1 = fmaf(uv.y, E[4 * i4 + 1], acc1);
            acc2 = fmaf(uv.z, E[4 * i4 + 2], acc2);
            acc3 = fmaf(uv.w, E[4 * i4 + 3], acc3);
        }
        float S = (acc0 + acc1) + (acc2 + acc3);
        float lg = __logf(S);
        lg = (S > 0.f) ? lg : NEGV;
        float a_t = em_t + (mPrev + lg);
        outb[t * Ln + j] = a_t;
        if (t == len - 1) aLast = a_t;
        u = S * cf;
        aPrev = a_t;
        mPrev = mNext;
    }
    float last = aLast + trEj;
    float m2 = last;
#pragma unroll
    for (int off = 32; off > 0; off >>= 1)
        m2 = fmaxf(m2, __shfl_xor(m2, off, 64));
    float e2 = __expf(last - m2);
#pragma unroll
    for (int off = 32; off > 0; off >>= 1)
        e2 += __shfl_xor(e2, off, 64);
    if (j == 0) out[(size_t)Bn * Tn * Ln + b] = m2 + __logf(e2);
}

extern "C" void kernel_launch(void* const* d_in, const int* in_sizes, int n_in,
                              void* d_out, int out_size, void* d_ws, size_t ws_size,
                              hipStream_t stream) {
    const float* em = (const float*)d_in[0];
    const float* tr = (const float*)d_in[1];
    const int* lens = (const int*)d_in[2];
    float* out = (float*)d_out;
    const size_t wsNeed = 2u * 64 * 16 * 64 * sizeof(float);   // 512 KiB
    if (ws_size >= wsNeed) {
        float* wsE = (float*)d_ws;
        float* wsS = wsE + 64 * 16 * 64;
        crf_passA<<<dim3(1024), dim3(128), 0, stream>>>(em, tr, out, wsE, wsS);
        crf_passB<<<dim3(64), dim3(64), 0, stream>>>(out, wsE, wsS);
        crf_passC<<<dim3(960), dim3(64), 0, stream>>>(em, tr, lens, out, wsE);
    } else {
        crf_fallback<<<dim3(Bn), dim3(64), 0, stream>>>(em, tr, lens, out);
    }
}